// Round 3
// baseline (1748.386 us; speedup 1.0000x reference)
//
#include <hip/hip_runtime.h>
#include <cstdint>
#include <cstddef>

#define B_ 4096
#define T_ 128
#define N_ 128
#define H_ 128
#define G4_ 512       // 4*H
#define KC_ 256       // concat K = [x|h]
#define EPS_ 1e-5f

#define RPB_ 16       // batch rows per block
#define NB_ 256       // blocks (one per CU)
#define W0K_ 128      // layer0 K-half staged in LDS (k = 0..127, the x-part)
#define APAD_ 136     // padded LDS stride (f16) for activation tiles: 272 B, 16B-aligned

typedef _Float16 f16x8 __attribute__((ext_vector_type(8)));
typedef _Float16 f16x4 __attribute__((ext_vector_type(4)));
typedef float f32x4 __attribute__((ext_vector_type(4)));

__device__ __forceinline__ float sigm_(float x) { return 1.f / (1.f + __expf(-x)); }
__device__ __forceinline__ float tanh_(float x) {
  float ax = fabsf(x);
  float e = __expf(-2.f * ax);
  float t = (1.f - e) / (1.f + e);
  return copysignf(t, x);
}

// ---------------- K0: pack weights to f16 [2][512][256] = [Wih | Whh], combine biases, zero stats
__global__ void k0_prep(const float* __restrict__ Wih0, const float* __restrict__ Whh0,
                        const float* __restrict__ bih0, const float* __restrict__ bhh0,
                        const float* __restrict__ Wih1, const float* __restrict__ Whh1,
                        const float* __restrict__ bih1, const float* __restrict__ bhh1,
                        _Float16* __restrict__ Wpack, float* __restrict__ bpack,
                        float* __restrict__ sumb, float* __restrict__ sqb) {
  int idx = blockIdx.x * blockDim.x + threadIdx.x;
  if (idx < 2 * G4_ * KC_) {
    int k = idx & (KC_ - 1);
    int j = (idx >> 8) & (G4_ - 1);
    int l = idx >> 17;
    const float* Wih = l ? Wih1 : Wih0;
    const float* Whh = l ? Whh1 : Whh0;
    float v = (k < N_) ? Wih[j * N_ + k] : Whh[j * N_ + (k - N_)];
    Wpack[idx] = (_Float16)v;
  }
  if (idx < 2 * G4_) {
    int j = idx & (G4_ - 1);
    bpack[idx] = (idx >> 9) ? (bih1[j] + bhh1[j]) : (bih0[j] + bhh0[j]);
  }
  if (idx < T_ * N_) { sumb[idx] = 0.f; sqb[idx] = 0.f; }
}

// ---------------- K1: score_x + softmax over n -> alpha[b][n]  (time-invariant)
// v3: stage X-block (64 KB) to LDS with f32x4 coalesced loads; column-sum from LDS.
__global__ void k1_alpha(const float* __restrict__ X, const float* __restrict__ attn_w,
                         const float* __restrict__ attn_b, float* __restrict__ alpha) {
  __shared__ float xs[T_ * N_];  // 64 KB
  __shared__ float wx[T_];
  __shared__ float ps[2][N_];
  __shared__ float red[8];
  int b = blockIdx.x;
  int tid = threadIdx.x;  // 0..255
  if (tid < T_) wx[tid] = attn_w[2 * H_ + tid];
  const float* xb = X + (size_t)b * T_ * N_;
#pragma unroll
  for (int i = 0; i < 16; ++i) {
    int fi = ((i << 8) + tid) << 2;
    *(f32x4*)&xs[fi] = *(const f32x4*)&xb[fi];
  }
  __syncthreads();
  int n = tid & 127, hf = tid >> 7;
  float s = 0.f;
  {
    int t0 = hf << 6;
#pragma unroll 8
    for (int tt = 0; tt < 64; ++tt) s = fmaf(xs[(t0 + tt) * N_ + n], wx[t0 + tt], s);
  }
  ps[hf][n] = s;
  __syncthreads();
  s = ps[0][n] + ps[1][n] + attn_b[0];
  float m = s;
#pragma unroll
  for (int off = 32; off >= 1; off >>= 1) m = fmaxf(m, __shfl_xor(m, off));
  int wv = tid >> 6;
  if ((tid & 63) == 0) red[wv] = m;
  __syncthreads();
  m = fmaxf(red[0], red[1]);
  float e = __expf(s - m);
  float sm = e;
#pragma unroll
  for (int off = 32; off >= 1; off >>= 1) sm += __shfl_xor(sm, off);
  if ((tid & 63) == 0) red[4 + wv] = sm;
  __syncthreads();
  sm = red[4] + red[5];
  if (hf == 0) alpha[b * N_ + n] = e / sm;
}

// ---------------- K2: X_tilde = alpha*X (write output 0) + BN partial stats per (t,n)
// v3: f32x4 (16 B/lane) loads/stores; LDS partial reduce; 2 atomics per (t,n) per block.
__global__ void k2_xtilde(const float* __restrict__ X, const float* __restrict__ alpha,
                          float* __restrict__ out0, float* __restrict__ sumb,
                          float* __restrict__ sqb) {
  int t = blockIdx.x;
  int chunk = blockIdx.y;
  int tid = threadIdx.x;         // 0..255
  int c = (tid & 31) << 2;       // 0..124
  int r = tid >> 5;              // 0..7
  f32x4 s4 = {}, q4 = {};
  for (int it = 0; it < 32; ++it) {
    int b = (chunk << 8) + (it << 3) + r;
    f32x4 a4 = *(const f32x4*)&alpha[b * N_ + c];
    size_t off = ((size_t)b * T_ + t) * N_ + c;
    f32x4 x4 = *(const f32x4*)&X[off];
    f32x4 v;
#pragma unroll
    for (int e = 0; e < 4; ++e) v[e] = a4[e] * x4[e];
    *(f32x4*)&out0[off] = v;
#pragma unroll
    for (int e = 0; e < 4; ++e) { s4[e] += v[e]; q4[e] += v[e] * v[e]; }
  }
  __shared__ float ps[8][N_], pq[8][N_];
  *(f32x4*)&ps[r][c] = s4;
  *(f32x4*)&pq[r][c] = q4;
  __syncthreads();
  if (tid < N_) {
    float s = 0.f, q = 0.f;
#pragma unroll
    for (int rr = 0; rr < 8; ++rr) { s += ps[rr][tid]; q += pq[rr][tid]; }
    atomicAdd(&sumb[t * N_ + tid], s);
    atomicAdd(&sqb[t * N_ + tid], q);
  }
}

// ---------------- K3: finalize BN -> per-(t,n) scale/shift
__global__ void k3_finalize(const float* __restrict__ sumb, const float* __restrict__ sqb,
                            const float* __restrict__ gamma, const float* __restrict__ beta,
                            float* __restrict__ scale, float* __restrict__ shift) {
  int i = blockIdx.x * blockDim.x + threadIdx.x;
  if (i >= T_ * N_) return;
  int n = i & (N_ - 1);
  float mean = sumb[i] * (1.f / B_);
  float var = sqb[i] * (1.f / B_) - mean * mean;
  float rstd = rsqrtf(var + EPS_);
  float g = gamma[n];
  scale[i] = rstd * g;
  shift[i] = beta[n] - mean * rstd * g;
}

// ---------------- K4: 2-layer LSTM recurrence, v3.
// 256 blocks x 16 rows, 8 waves. Wave w owns output cols [w*16,w*16+16), all 4 gates.
// w1 (layer1 weights) forced VGPR-resident via volatile loads (128 VGPR).
// W0 x-half in XOR-swizzled LDS; W0 h-half streamed from L2 each step (asm-opaque index
// prevents LICM hoist). 2 barriers/step via split single/double LDS buffers.
__global__ __launch_bounds__(512, 2) void k4_recur(
    const float* __restrict__ xt /* X_tilde */, const _Float16* __restrict__ Wpack,
    const float* __restrict__ bpack, const float* __restrict__ scale,
    const float* __restrict__ shift, float* __restrict__ out1) {
  __shared__ _Float16 W0l[G4_ * 128];      // 131072 B, XOR-swizzled rows of 256 B
  __shared__ _Float16 XB[RPB_][APAD_];     // xb(t)            (single buffer)
  __shared__ _Float16 H0A[2][RPB_][APAD_]; // h0  -> GEMM0 in  (double)
  __shared__ _Float16 H0B[RPB_][APAD_];    // h0n -> GEMM1 in  (single, same-step RAW)
  __shared__ _Float16 H1[2][RPB_][APAD_];  // h1  -> GEMM1 in  (double)
  // total LDS = 131072 + 6*16*136*2 = 157184 B

  const int tid = threadIdx.x;
  const int w = tid >> 6;
  const int lane = tid & 63;
  const int quad = lane >> 4;
  const int l16 = lane & 15;
  const int nb = blockIdx.x;
  const int col = (w << 4) + l16;  // output col owned by this lane

  // ---- one-time: stage W0 x-half into LDS, swizzled (row r: byte ^= (r&7)<<4)
  {
    const _Float16* src = Wpack + (size_t)tid * KC_;
    char* dst = (char*)W0l + tid * 256;
    const int sw = (tid & 7) << 4;
#pragma unroll
    for (int o = 0; o < 256; o += 16)
      *(f16x8*)(dst + (o ^ sw)) = *(const f16x8*)((const char*)src + o);
  }

  // ---- layer-1 weights resident: volatile loads (no remat/hoist possible). 128 VGPR.
  f16x8 w1[4][8];
#pragma unroll
  for (int g = 0; g < 4; ++g) {
    const _Float16* src = Wpack + (size_t)(G4_ + (g << 7) + col) * KC_ + (quad << 3);
#pragma unroll
    for (int kb = 0; kb < 8; ++kb)
      w1[g][kb] = *(volatile const f16x8*)&src[kb << 5];
  }

  float bia0[4], bia1[4];
#pragma unroll
  for (int g = 0; g < 4; ++g) {
    bia0[g] = bpack[(g << 7) + col];
    bia1[g] = bpack[G4_ + (g << 7) + col];
  }

  float c0[4], c1[4];
#pragma unroll
  for (int e = 0; e < 4; ++e) { c0[e] = 0.f; c1[e] = 0.f; }

  // staging coords: each thread stages 4 floats of one row
  const int sr = tid >> 5;          // 0..15
  const int sc = (tid & 31) << 2;   // 0..124
  const size_t browbase = (size_t)(nb * RPB_ + sr) * T_;

  // prologue: stage xb(0), zero h-buffers (buffer 0)
  {
    f32x4 xv = *(const f32x4*)(xt + (browbase + 0) * N_ + sc);
    f32x4 s4 = *(const f32x4*)(scale + sc);
    f32x4 h4 = *(const f32x4*)(shift + sc);
    f16x4 hv;
#pragma unroll
    for (int e = 0; e < 4; ++e) hv[e] = (_Float16)fmaf(xv[e], s4[e], h4[e]);
    *(f16x4*)&XB[sr][sc] = hv;
    f16x4 z = {};
    *(f16x4*)&H0A[0][sr][sc] = z;
    *(f16x4*)&H1[0][sr][sc] = z;
  }
  __syncthreads();

  const int swr = (l16 & 7) << 4;  // read-side swizzle for W0l (row & 7 == l16 & 7)

  for (int t = 0; t < T_; ++t) {
    const int cb = t & 1, cbn = cb ^ 1;

    // opaque zero: makes streamed-W0h addresses loop-variant (blocks LICM hoist)
    int z = 0;
    asm volatile("" : "+v"(z));

    // prefetch x(t+1); consumed after B-mid in act1 phase
    f32x4 xn = {};
    if (t + 1 < T_) xn = *(const f32x4*)(xt + (browbase + t + 1) * N_ + sc);

    // ---- GEMM0: gates0 = [xb|h0] @ W0^T
    f16x8 a[8];
#pragma unroll
    for (int kb = 0; kb < 4; ++kb) {
      a[kb] = *(const f16x8*)&XB[l16][(kb << 5) + (quad << 3)];
      a[4 + kb] = *(const f16x8*)&H0A[cb][l16][(kb << 5) + (quad << 3)];
    }
    f32x4 acc[4] = {};
#pragma unroll
    for (int g = 0; g < 4; ++g) {
      // streamed W0 h-half (k = 128..255) from L2, issued ahead of this g's MFMAs
      const _Float16* wpg =
          Wpack + (size_t)((g << 7) + col) * KC_ + W0K_ + (quad << 3) + z;
      f16x8 b4 = *(const f16x8*)&wpg[0];
      f16x8 b5 = *(const f16x8*)&wpg[32];
      f16x8 b6 = *(const f16x8*)&wpg[64];
      f16x8 b7 = *(const f16x8*)&wpg[96];
      // W0 x-half from swizzled LDS
      const char* wr = (const char*)W0l + (((g << 7) + col) << 8);
      f16x8 b0 = *(const f16x8*)(wr + (((0 << 6) | (quad << 4)) ^ swr));
      f16x8 b1 = *(const f16x8*)(wr + (((1 << 6) | (quad << 4)) ^ swr));
      f16x8 b2 = *(const f16x8*)(wr + (((2 << 6) | (quad << 4)) ^ swr));
      f16x8 b3 = *(const f16x8*)(wr + (((3 << 6) | (quad << 4)) ^ swr));
      acc[g] = __builtin_amdgcn_mfma_f32_16x16x32_f16(a[0], b0, acc[g], 0, 0, 0);
      acc[g] = __builtin_amdgcn_mfma_f32_16x16x32_f16(a[1], b1, acc[g], 0, 0, 0);
      acc[g] = __builtin_amdgcn_mfma_f32_16x16x32_f16(a[2], b2, acc[g], 0, 0, 0);
      acc[g] = __builtin_amdgcn_mfma_f32_16x16x32_f16(a[3], b3, acc[g], 0, 0, 0);
      acc[g] = __builtin_amdgcn_mfma_f32_16x16x32_f16(a[4], b4, acc[g], 0, 0, 0);
      acc[g] = __builtin_amdgcn_mfma_f32_16x16x32_f16(a[5], b5, acc[g], 0, 0, 0);
      acc[g] = __builtin_amdgcn_mfma_f32_16x16x32_f16(a[6], b6, acc[g], 0, 0, 0);
      acc[g] = __builtin_amdgcn_mfma_f32_16x16x32_f16(a[7], b7, acc[g], 0, 0, 0);
    }

    // ---- act0 (register-only). acc row = quad*4+e, col = this lane's col.
    _Float16 h0h[4];
#pragma unroll
    for (int e = 0; e < 4; ++e) {
      float ig = acc[0][e] + bia0[0];
      float fg = acc[1][e] + bia0[1];
      float gg = acc[2][e] + bia0[2];
      float og = acc[3][e] + bia0[3];
      float cn = sigm_(fg) * c0[e] + sigm_(ig) * tanh_(gg);
      c0[e] = cn;
      h0h[e] = (_Float16)(sigm_(og) * tanh_(cn));
    }
#pragma unroll
    for (int e = 0; e < 4; ++e) {
      H0A[cbn][(quad << 2) + e][col] = h0h[e];  // h0 for next step's GEMM0
      H0B[(quad << 2) + e][col] = h0h[e];       // h0n for this step's GEMM1
    }
    __syncthreads();  // B-mid: H0B ready; all GEMM0 LDS reads complete

    // ---- GEMM1: gates1 = [h0n|h1] @ W1^T ; B entirely from resident registers
    f16x8 a1[8];
#pragma unroll
    for (int kb = 0; kb < 4; ++kb) {
      a1[kb] = *(const f16x8*)&H0B[l16][(kb << 5) + (quad << 3)];
      a1[4 + kb] = *(const f16x8*)&H1[cb][l16][(kb << 5) + (quad << 3)];
    }
    f32x4 acc1[4] = {};
#pragma unroll
    for (int g = 0; g < 4; ++g) {
      acc1[g] = __builtin_amdgcn_mfma_f32_16x16x32_f16(a1[0], w1[g][0], acc1[g], 0, 0, 0);
      acc1[g] = __builtin_amdgcn_mfma_f32_16x16x32_f16(a1[1], w1[g][1], acc1[g], 0, 0, 0);
      acc1[g] = __builtin_amdgcn_mfma_f32_16x16x32_f16(a1[2], w1[g][2], acc1[g], 0, 0, 0);
      acc1[g] = __builtin_amdgcn_mfma_f32_16x16x32_f16(a1[3], w1[g][3], acc1[g], 0, 0, 0);
      acc1[g] = __builtin_amdgcn_mfma_f32_16x16x32_f16(a1[4], w1[g][4], acc1[g], 0, 0, 0);
      acc1[g] = __builtin_amdgcn_mfma_f32_16x16x32_f16(a1[5], w1[g][5], acc1[g], 0, 0, 0);
      acc1[g] = __builtin_amdgcn_mfma_f32_16x16x32_f16(a1[6], w1[g][6], acc1[g], 0, 0, 0);
      acc1[g] = __builtin_amdgcn_mfma_f32_16x16x32_f16(a1[7], w1[g][7], acc1[g], 0, 0, 0);
    }

    // ---- act1 + output store
    _Float16 h1h[4];
#pragma unroll
    for (int e = 0; e < 4; ++e) {
      float ig = acc1[0][e] + bia1[0];
      float fg = acc1[1][e] + bia1[1];
      float gg = acc1[2][e] + bia1[2];
      float og = acc1[3][e] + bia1[3];
      float cn = sigm_(fg) * c1[e] + sigm_(ig) * tanh_(gg);
      c1[e] = cn;
      float hn = sigm_(og) * tanh_(cn);
      h1h[e] = (_Float16)hn;
      out1[((size_t)(nb * RPB_ + (quad << 2) + e) * T_ + t) * H_ + col] = hn;
    }
#pragma unroll
    for (int e = 0; e < 4; ++e)
      H1[cbn][(quad << 2) + e][col] = h1h[e];  // h1 for next step's GEMM1
    if (t + 1 < T_) {  // stage xb(t+1) into XB (single buffer: GEMM0 reads done pre-B-mid)
      f32x4 s4 = *(const f32x4*)(scale + (t + 1) * N_ + sc);
      f32x4 h4 = *(const f32x4*)(shift + (t + 1) * N_ + sc);
      f16x4 hv;
#pragma unroll
      for (int e = 0; e < 4; ++e) hv[e] = (_Float16)fmaf(xn[e], s4[e], h4[e]);
      *(f16x4*)&XB[sr][sc] = hv;
    }
    __syncthreads();  // B-end: XB/H0A/H1 ready for next step
  }
}

extern "C" void kernel_launch(void* const* d_in, const int* in_sizes, int n_in,
                              void* d_out, int out_size, void* d_ws, size_t ws_size,
                              hipStream_t stream) {
  const float* X = (const float*)d_in[0];
  const float* attnw = (const float*)d_in[1];
  const float* attnb = (const float*)d_in[2];
  const float* gamma = (const float*)d_in[3];
  const float* beta = (const float*)d_in[4];
  const float* Wih0 = (const float*)d_in[5];
  const float* Whh0 = (const float*)d_in[6];
  const float* bih0 = (const float*)d_in[7];
  const float* bhh0 = (const float*)d_in[8];
  const float* Wih1 = (const float*)d_in[9];
  const float* Whh1 = (const float*)d_in[10];
  const float* bih1 = (const float*)d_in[11];
  const float* bhh1 = (const float*)d_in[12];

  float* out0 = (float*)d_out;                    // X_tilde
  float* out1 = out0 + (size_t)B_ * T_ * N_;      // X_encoded

  float* ws = (float*)d_ws;
  float* alpha = ws;                              // B*N
  float* sumb = alpha + (size_t)B_ * N_;          // T*N
  float* sqb = sumb + T_ * N_;
  float* scale = sqb + T_ * N_;
  float* shift = scale + T_ * N_;
  float* bpack = shift + T_ * N_;                 // 2*512
  _Float16* Wpack = (_Float16*)(bpack + 2 * G4_); // 2*512*256 f16 (16B-aligned)

  k0_prep<<<1024, 256, 0, stream>>>(Wih0, Whh0, bih0, bhh0, Wih1, Whh1, bih1, bhh1,
                                    Wpack, bpack, sumb, sqb);
  k1_alpha<<<B_, 256, 0, stream>>>(X, attnw, attnb, alpha);
  k2_xtilde<<<dim3(T_, 16), 256, 0, stream>>>(X, alpha, out0, sumb, sqb);
  k3_finalize<<<64, 256, 0, stream>>>(sumb, sqb, gamma, beta, scale, shift);
  k4_recur<<<NB_, 512, 0, stream>>>(out0, Wpack, bpack, scale, shift, out1);
}